// Round 8
// baseline (112.764 us; speedup 1.0000x reference)
//
#include <hip/hip_runtime.h>

#define N2 4096
#define D 128
#define TAU_INV 10.0f
#define E2SCALE 14.4269504088896340736f   // 10 * log2(e): exp(10x) = exp2(x*E2SCALE)
#define JS 32                     // j-slices per 64-row i-block; slice = 128 cols
#define GEMM_BLOCKS (64 * JS)     // 2048
#define NCLS 10
#define CGRP 16                   // row-groups per class
#define CROWS (N2 / CGRP)         // 256 rows per class block
#define CB (NCLS * CGRP)          // 160 class blocks (scheduled FIRST)

typedef __attribute__((ext_vector_type(8))) short bf16x8;
typedef __attribute__((ext_vector_type(4))) float floatx4;

__device__ __forceinline__ short f2bf(float f) {
    unsigned u = __float_as_uint(f);
    u = (u + 0x7fff + ((u >> 16) & 1)) >> 16;   // RNE
    return (short)u;
}
__device__ __forceinline__ float bf2f(short s) {
    return __uint_as_float(((unsigned)(unsigned short)s) << 16);
}

// Normalize rows of p = concat(z_i, z_j) in fp32, emit bf16 Q.
// One row per 64-thread block. Also zeroes se_g and block 0 zeroes S/T/CNT.
__global__ __launch_bounds__(64) void prep_kernel(const float* __restrict__ zi,
                                                  const float* __restrict__ zj,
                                                  short* __restrict__ qb,
                                                  float* __restrict__ se_g,
                                                  float* __restrict__ S) {   // S,T,CNT contiguous: 1300 floats
    int row = blockIdx.x;
    int lane = threadIdx.x;                    // 64 lanes, 2 floats each
    const float* src = (row < 2048) ? (zi + row * D) : (zj + (row - 2048) * D);
    float2 v = ((const float2*)src)[lane];
    float ss = v.x * v.x + v.y * v.y;
    #pragma unroll
    for (int m = 1; m < 64; m <<= 1) ss += __shfl_xor(ss, m);
    float inv = 1.0f / sqrtf(ss);              // ||p|| ~ sqrt(128) >> eps
    short2 o;
    o.x = f2bf(v.x * inv);
    o.y = f2bf(v.y * inv);
    ((short2*)(qb + row * D))[lane] = o;
    if (lane == 0) se_g[row] = 0.f;
    if (row == 0)
        for (int k = lane; k < NCLS * D + 2 * NCLS; k += 64) S[k] = 0.f;
}

// Grid = 160 class blocks (first) + 2048 GEMM blocks.
//
// GEMM block gb: i-block of 64 rows (4 waves x 16-row strips) x one 128-col
// j-slice (8 tiles of 16 cols). MFMA 16x16x32 bf16, K=128 (4 chained steps).
// Fragments (16x16x32): A lane holds row=lane&15, 8 bf16 at k=(lane>>4)*8;
// B same (Gram matrix: B-col n = qb row j0+n). C/D: col=lane&15,
// row=(lane>>4)*4+reg. Small state (~64 VGPR) -> 6 waves/SIMD occupancy:
// this kernel has been latency-bound at <=31% occupancy all session.
// Accumulates only se (exp-sum); diagonal tile (j0==rbase) is wave-uniform.
//
// Class block cb (class c, row-group g): masked sums over 256 rows of qb.
// Labels used as VALUES only; all addresses structural -> poison-safe.
__global__ __launch_bounds__(256, 6) void main_kernel(const short* __restrict__ qb,
                                                      const long long* __restrict__ y,
                                                      float* __restrict__ se_g,
                                                      float* __restrict__ S) {
    int tid = threadIdx.x;

    if (blockIdx.x < CB) {
        // ---- class-sum path ----
        int cb = blockIdx.x;                 // 0..159
        int c  = cb / CGRP;                  // 0..9
        int g  = cb % CGRP;                  // 0..15
        int d  = tid & 127;
        int rh = tid >> 7;                   // 0/1
        int r0 = g * CROWS + rh * (CROWS / 2);

        float sS = 0.f, sT = 0.f, cnt = 0.f;
        #pragma unroll 4
        for (int i = 0; i < CROWS / 2; ++i) {
            int r = r0 + i;
            bool m = ((int)y[r & 2047] == c);      // wave-uniform broadcast
            float q = bf2f(qb[r * D + d]);         // coalesced 128B per wave
            sS += m ? q : 0.f;
            sT += m ? q * q : 0.f;
            cnt += m ? 1.f : 0.f;
        }

        __shared__ float shS[256];
        __shared__ float shT[4];
        __shared__ float shC[2];
        shS[tid] = sS;
        #pragma unroll
        for (int m = 1; m < 64; m <<= 1) sT += __shfl_xor(sT, m);
        if ((tid & 63) == 0) shT[tid >> 6] = sT;
        if (d == 0) shC[rh] = cnt;
        __syncthreads();
        if (tid < 128) atomicAdd(&S[c * D + tid], shS[tid] + shS[tid + 128]);
        if (tid == 0) {
            atomicAdd(&S[NCLS * D + c], shT[0] + shT[1] + shT[2] + shT[3]);   // T_c
            atomicAdd(&S[NCLS * D + NCLS + c], shC[0] + shC[1]);              // CNT_c
        }
        return;
    }

    // ---- GEMM path ----
    int gb = blockIdx.x - CB;          // 0..2047
    int wave = tid >> 6;
    int lane = tid & 63;
    int rlo  = lane & 15;              // fragment row/col
    int khi  = lane >> 4;              // 0..3: k-chunk
    int it = gb >> 5;                  // 0..63  (64-row i-block)
    int js = gb & (JS - 1);            // 0..31
    int rbase = it * 64 + wave * 16;   // this wave's 16 i-rows
    int jbase = js * 128;

    // A fragments: 16 rows x K=128 (4 chained MFMA steps), 16 VGPR total
    const short* aptr = qb + (rbase + rlo) * D + khi * 8;
    bf16x8 af[4];
    #pragma unroll
    for (int kk = 0; kk < 4; ++kk) af[kk] = *(const bf16x8*)(aptr + kk * 32);

    float se0 = 0.f, se1 = 0.f, se2 = 0.f, se3 = 0.f;

    #pragma unroll
    for (int t = 0; t < 8; ++t) {
        int j0 = jbase + t * 16;
        const short* bptr = qb + (j0 + rlo) * D + khi * 8;
        bf16x8 b0 = *(const bf16x8*)(bptr);
        bf16x8 b1 = *(const bf16x8*)(bptr + 32);
        bf16x8 b2 = *(const bf16x8*)(bptr + 64);
        bf16x8 b3 = *(const bf16x8*)(bptr + 96);

        floatx4 acc = {0.f, 0.f, 0.f, 0.f};
        acc = __builtin_amdgcn_mfma_f32_16x16x32_bf16(af[0], b0, acc, 0, 0, 0);
        acc = __builtin_amdgcn_mfma_f32_16x16x32_bf16(af[1], b1, acc, 0, 0, 0);
        acc = __builtin_amdgcn_mfma_f32_16x16x32_bf16(af[2], b2, acc, 0, 0, 0);
        acc = __builtin_amdgcn_mfma_f32_16x16x32_bf16(af[3], b3, acc, 0, 0, 0);

        if (j0 == rbase) {                    // wave-uniform: diagonal tile
            #pragma unroll
            for (int r = 0; r < 4; ++r) {
                float e = __builtin_amdgcn_exp2f(acc[r] * E2SCALE);
                e = (khi * 4 + r == rlo) ? 0.f : e;    // exclude self-pair
                if (r == 0) se0 += e; else if (r == 1) se1 += e;
                else if (r == 2) se2 += e; else se3 += e;
            }
        } else {
            se0 += __builtin_amdgcn_exp2f(acc[0] * E2SCALE);
            se1 += __builtin_amdgcn_exp2f(acc[1] * E2SCALE);
            se2 += __builtin_amdgcn_exp2f(acc[2] * E2SCALE);
            se3 += __builtin_amdgcn_exp2f(acc[3] * E2SCALE);
        }
    }

    // reduce each se over the 16 cols (xor 1,2,4,8 stays in 16-lane group)
    #pragma unroll
    for (int m = 1; m < 16; m <<= 1) {
        se0 += __shfl_xor(se0, m);
        se1 += __shfl_xor(se1, m);
        se2 += __shfl_xor(se2, m);
        se3 += __shfl_xor(se3, m);
    }
    if (rlo == 0) {                           // lanes 0,16,32,48: 4 rows each
        int rowr = rbase + khi * 4;
        atomicAdd(&se_g[rowr + 0], se0);
        atomicAdd(&se_g[rowr + 1], se1);
        atomicAdd(&se_g[rowr + 2], se2);
        atomicAdd(&se_g[rowr + 3], se3);
    }
}

// loss = (sum_i log se_i  -  sum_c 10*(||S_c||^2 - T_c)/(n_c-1)) / N2
__global__ __launch_bounds__(256) void finish_kernel(const float* __restrict__ se_g,
                                                     const float* __restrict__ S,
                                                     float* __restrict__ out) {
    int tid = threadIdx.x;
    int wave = tid >> 6;
    int lane = tid & 63;

    // positive-pair term: wave w handles classes w, w+4, w+8
    float P = 0.f;
    for (int c = wave; c < NCLS; c += 4) {
        float2 sv = ((const float2*)(S + c * D))[lane];
        float s2 = sv.x * sv.x + sv.y * sv.y;
        #pragma unroll
        for (int m = 1; m < 64; m <<= 1) s2 += __shfl_xor(s2, m);
        float n = S[NCLS * D + NCLS + c];
        P += (n >= 2.0f) ? (s2 - S[NCLS * D + c]) * TAU_INV / (n - 1.0f) : 0.f;
    }

    // denominator term
    float L = 0.f;
    for (int i = tid; i < N2; i += 256) L += __logf(se_g[i]);
    #pragma unroll
    for (int m = 1; m < 64; m <<= 1) L += __shfl_xor(L, m);

    __shared__ float red[8];
    if (lane == 0) { red[wave] = L; red[4 + wave] = P; }
    __syncthreads();
    if (tid == 0) {
        float Ls = red[0] + red[1] + red[2] + red[3];
        float Ps = red[4] + red[5] + red[6] + red[7];
        out[0] = (Ls - Ps) * (1.0f / (float)N2);
    }
}

extern "C" void kernel_launch(void* const* d_in, const int* in_sizes, int n_in,
                              void* d_out, int out_size, void* d_ws, size_t ws_size,
                              hipStream_t stream) {
    const float*     zi = (const float*)d_in[0];
    const float*     zj = (const float*)d_in[1];
    const long long* y  = (const long long*)d_in[2];
    float* out = (float*)d_out;

    char* ws = (char*)d_ws;
    short* qb   = (short*)ws;                               // 4096*128*2B = 1 MB
    float* se_g = (float*)(ws + N2 * D * sizeof(short));    // 16 KB
    float* S    = se_g + N2;                                // S[10][128] + T[10] + CNT[10] = 1300 f32

    prep_kernel<<<N2, 64, 0, stream>>>(zi, zj, qb, se_g, S);
    main_kernel<<<CB + GEMM_BLOCKS, 256, 0, stream>>>(qb, y, se_g, S);
    finish_kernel<<<1, 256, 0, stream>>>(se_g, S, out);
}